// Round 1
// baseline (505.847 us; speedup 1.0000x reference)
//
#include <hip/hip_runtime.h>
#include <hip/hip_bf16.h>

#define H   256
#define HH  128
#define TM  64

typedef _Float16 h2 __attribute__((ext_vector_type(2)));
typedef _Float16 h8 __attribute__((ext_vector_type(8)));

#define H2OF(v,i) __builtin_shufflevector(v, v, 2*(i), 2*(i)+1)

#if __has_builtin(__builtin_amdgcn_fdot2)
#define FDOT2(a,b,c) __builtin_amdgcn_fdot2((a),(b),(c),false)
#else
static __device__ __forceinline__ float FDOT2(h2 a, h2 b, float c) {
    return c + (float)a[0]*(float)b[0] + (float)a[1]*(float)b[1];
}
#endif

// ---------------------------------------------------------------- K0: pack weights
// aW1P: h2[ko][j][s], ko=0..31, j=0..127, s=0..3; value = (aW1[k][j], aW1[k+1][j]), k=ko*8+s*2
// gW1P: f32[kq][j][s], kq=0..63, j=0..255, s=0..3; value = gW1[(kq*4+s)*256 + j]
// gW2P: f32[kq][j][s], kq=0..63, j=0..127, s=0..3; value = gW2[(kq*4+s)*128 + j]
__global__ __launch_bounds__(256) void k0_pack(
    const float* __restrict__ aW1, const float* __restrict__ gW1,
    const float* __restrict__ gW2,
    h2* __restrict__ aW1P, float* __restrict__ gW1P, float* __restrict__ gW2P)
{
    int idx = blockIdx.x * 256 + threadIdx.x;
    int stride = gridDim.x * 256;
    for (int e = idx; e < 32*128*4; e += stride) {
        int s = e & 3, j = (e >> 2) & 127, ko = e >> 9;
        int k = ko*8 + s*2;
        h2 v;
        v[0] = (_Float16)aW1[k*128 + j];
        v[1] = (_Float16)aW1[(k+1)*128 + j];
        aW1P[e] = v;
    }
    for (int e = idx; e < 64*256*4; e += stride) {
        int s = e & 3, j = (e >> 2) & 255, kq = e >> 10;
        gW1P[e] = gW1[(kq*4+s)*256 + j];
    }
    for (int e = idx; e < 64*128*4; e += stride) {
        int s = e & 3, j = (e >> 2) & 127, kq = e >> 9;
        gW2P[e] = gW2[(kq*4+s)*128 + j];
    }
}

// ---------------------------------------------------------------- K1: fused score MLP -> logits[N]
// block: 256 thr, 64 orbitals. thread t: quarter q=t>>6 (16 orbitals), jj=t&63 -> hidden j0=2*jj, j0+1
__global__ __launch_bounds__(256) void k1_scores(
    const float* __restrict__ emb, const h2* __restrict__ aW1P,
    const float* __restrict__ ab1, const float* __restrict__ aW2,
    const float* __restrict__ ab2, float* __restrict__ logits, int N)
{
    __shared__ __align__(16) h2 embh[TM * HH];   // [m][kk], 32 KB
    int t = threadIdx.x;
    long tile0 = (long)blockIdx.x * TM;

    // stage tile as half2 (zero-fill tail)
    #pragma unroll
    for (int i = 0; i < 16; ++i) {
        int f = t + i*256;              // float4 index within tile, 0..4095
        int m = f >> 6;
        long row = tile0 + m;
        float4 v = make_float4(0.f, 0.f, 0.f, 0.f);
        if (row < N) v = reinterpret_cast<const float4*>(emb)[row*(H/4) + (f & 63)];
        h2 a, b;
        a[0] = (_Float16)v.x; a[1] = (_Float16)v.y;
        b[0] = (_Float16)v.z; b[1] = (_Float16)v.w;
        embh[f*2]   = a;
        embh[f*2+1] = b;
    }
    __syncthreads();

    int q = t >> 6, jj = t & 63;
    int j0 = jj * 2;
    float acc0[16], acc1[16];
    #pragma unroll
    for (int m = 0; m < 16; ++m) { acc0[m] = 0.f; acc1[m] = 0.f; }

    const h2* wb = aW1P;
    #pragma unroll 2
    for (int ko = 0; ko < 32; ++ko) {
        h8 w0 = *reinterpret_cast<const h8*>(wb + ko*512 + j0*4);
        h8 w1 = *reinterpret_cast<const h8*>(wb + ko*512 + j0*4 + 4);
        #pragma unroll
        for (int m = 0; m < 16; ++m) {
            h8 e = *reinterpret_cast<const h8*>(&embh[(q*16 + m)*HH + ko*4]);
            acc0[m] = FDOT2(H2OF(e,0), H2OF(w0,0), acc0[m]);
            acc0[m] = FDOT2(H2OF(e,1), H2OF(w0,1), acc0[m]);
            acc0[m] = FDOT2(H2OF(e,2), H2OF(w0,2), acc0[m]);
            acc0[m] = FDOT2(H2OF(e,3), H2OF(w0,3), acc0[m]);
            acc1[m] = FDOT2(H2OF(e,0), H2OF(w1,0), acc1[m]);
            acc1[m] = FDOT2(H2OF(e,1), H2OF(w1,1), acc1[m]);
            acc1[m] = FDOT2(H2OF(e,2), H2OF(w1,2), acc1[m]);
            acc1[m] = FDOT2(H2OF(e,3), H2OF(w1,3), acc1[m]);
        }
    }

    // epilogue: bias, relu, dot with aW2, reduce across 64 lanes
    float b0 = ab1[j0], b1 = ab1[j0+1];
    float w20 = aW2[j0], w21 = aW2[j0+1];
    float p[16];
    #pragma unroll
    for (int m = 0; m < 16; ++m) {
        float h0 = acc0[m] + b0; h0 = h0 > 0.f ? h0 : 0.f;
        float h1 = acc1[m] + b1; h1 = h1 > 0.f ? h1 : 0.f;
        p[m] = h0*w20 + h1*w21;
    }
    #pragma unroll
    for (int off = 32; off >= 1; off >>= 1) {
        #pragma unroll
        for (int m = 0; m < 16; ++m) p[m] += __shfl_xor(p[m], off, 64);
    }
    if (jj == 0) {
        float bo = ab2[0];
        #pragma unroll
        for (int m = 0; m < 16; ++m) {
            long row = tile0 + q*16 + m;
            if (row < N) logits[row] = p[m] + bo;
        }
    }
}

// ---------------------------------------------------------------- K2: segment softmax + weighted pool
__global__ __launch_bounds__(256) void k2_pool(
    const float* __restrict__ emb, const int* __restrict__ batch,
    const float* __restrict__ logits, float* __restrict__ mol, int N)
{
    int m = blockIdx.x;
    int t = threadIdx.x;

    // segment bounds via binary search (batch sorted ascending)
    int lo = 0, hi = N;
    while (lo < hi) { int mid = (lo + hi) >> 1; if (batch[mid] < m) lo = mid + 1; else hi = mid; }
    int start = lo;
    hi = N;
    while (lo < hi) { int mid = (lo + hi) >> 1; if (batch[mid] < m + 1) lo = mid + 1; else hi = mid; }
    int end = lo;

    if (start >= end) { mol[(long)m*H + t] = 0.f; return; }

    __shared__ float red[8];
    __shared__ float wl[1024];

    // max
    float mx = -INFINITY;
    for (int i = start + t; i < end; i += 256) mx = fmaxf(mx, logits[i]);
    #pragma unroll
    for (int off = 32; off >= 1; off >>= 1) mx = fmaxf(mx, __shfl_xor(mx, off, 64));
    if ((t & 63) == 0) red[t >> 6] = mx;
    __syncthreads();
    mx = fmaxf(fmaxf(red[0], red[1]), fmaxf(red[2], red[3]));
    __syncthreads();

    // denom
    float s = 0.f;
    for (int i = start + t; i < end; i += 256) s += __expf(logits[i] - mx);
    #pragma unroll
    for (int off = 32; off >= 1; off >>= 1) s += __shfl_xor(s, off, 64);
    if ((t & 63) == 0) red[t >> 6] = s;
    __syncthreads();
    s = red[0] + red[1] + red[2] + red[3];
    float inv = 1.0f / s;

    // weighted sum; thread t owns embedding dim t
    float acc = 0.f;
    for (int c = start; c < end; c += 1024) {
        int cnt = min(1024, end - c);
        __syncthreads();
        for (int ii = t; ii < cnt; ii += 256) wl[ii] = __expf(logits[c + ii] - mx) * inv;
        __syncthreads();
        #pragma unroll 4
        for (int ii = 0; ii < cnt; ++ii) acc += wl[ii] * emb[(long)(c + ii)*H + t];
    }
    mol[(long)m*H + t] = acc;
}

// ---------------------------------------------------------------- K3: molecule MLP -> out[M]
// block: 32 molecules, 256 thr. thread t: j=t&127, mh=t>>7 (16 mols)
__global__ __launch_bounds__(256) void k3_mlp(
    const float* __restrict__ mol, const float* __restrict__ gW1P,
    const float* __restrict__ gb1, const float* __restrict__ gW2P,
    const float* __restrict__ gb2, const float* __restrict__ gW3,
    const float* __restrict__ gb3, float* __restrict__ out, int M)
{
    __shared__ __align__(16) float mt[32 * 256];
    __shared__ __align__(16) float g1[32 * 256];
    __shared__ float tmp[4][16];
    int t = threadIdx.x;
    int blk = blockIdx.x;

    #pragma unroll
    for (int i = 0; i < 8; ++i) {
        int f = t + i*256;             // float4 idx, 0..2047
        long gidx = (long)blk*2048 + f;
        float4 v = make_float4(0.f,0.f,0.f,0.f);
        if (gidx < (long)M*64) v = reinterpret_cast<const float4*>(mol)[gidx];
        reinterpret_cast<float4*>(mt)[f] = v;
    }
    __syncthreads();

    int j = t & 127, mh = t >> 7;

    // layer 1: 256 hidden (j and j+128)
    float a0[16], a1[16];
    #pragma unroll
    for (int m = 0; m < 16; ++m) { a0[m] = 0.f; a1[m] = 0.f; }
    for (int kq = 0; kq < 64; ++kq) {
        float4 w0 = reinterpret_cast<const float4*>(gW1P)[kq*256 + j];
        float4 w1 = reinterpret_cast<const float4*>(gW1P)[kq*256 + j + 128];
        #pragma unroll
        for (int m = 0; m < 16; ++m) {
            float4 e = *reinterpret_cast<const float4*>(&mt[(mh*16 + m)*256 + kq*4]);
            a0[m] += e.x*w0.x + e.y*w0.y + e.z*w0.z + e.w*w0.w;
            a1[m] += e.x*w1.x + e.y*w1.y + e.z*w1.z + e.w*w1.w;
        }
    }
    {
        float b0 = gb1[j], b1 = gb1[j + 128];
        #pragma unroll
        for (int m = 0; m < 16; ++m) {
            float v0 = a0[m] + b0; v0 = v0 > 0.f ? v0 : 0.f;
            float v1 = a1[m] + b1; v1 = v1 > 0.f ? v1 : 0.f;
            g1[(mh*16 + m)*256 + j]       = v0;
            g1[(mh*16 + m)*256 + j + 128] = v1;
        }
    }
    __syncthreads();

    // layer 2: 128 hidden (j2 = j)
    float a2[16];
    #pragma unroll
    for (int m = 0; m < 16; ++m) a2[m] = 0.f;
    for (int kq = 0; kq < 64; ++kq) {
        float4 w = reinterpret_cast<const float4*>(gW2P)[kq*128 + j];
        #pragma unroll
        for (int m = 0; m < 16; ++m) {
            float4 e = *reinterpret_cast<const float4*>(&g1[(mh*16 + m)*256 + kq*4]);
            a2[m] += e.x*w.x + e.y*w.y + e.z*w.z + e.w*w.w;
        }
    }

    // layer 3 + reduce
    float b2 = gb2[j], w3 = gW3[j];
    float p[16];
    #pragma unroll
    for (int m = 0; m < 16; ++m) {
        float v = a2[m] + b2; v = v > 0.f ? v : 0.f;
        p[m] = v * w3;
    }
    #pragma unroll
    for (int off = 32; off >= 1; off >>= 1) {
        #pragma unroll
        for (int m = 0; m < 16; ++m) p[m] += __shfl_xor(p[m], off, 64);
    }
    int wid = t >> 6;
    if ((t & 63) == 0) {
        #pragma unroll
        for (int m = 0; m < 16; ++m) tmp[wid][m] = p[m];
    }
    __syncthreads();
    if (t < 32) {
        int om = blk*32 + t;
        if (om < M) out[om] = tmp[(t >> 4)*2][t & 15] + tmp[(t >> 4)*2 + 1][t & 15] + gb3[0];
    }
}

// ---------------------------------------------------------------- launch
extern "C" void kernel_launch(void* const* d_in, const int* in_sizes, int n_in,
                              void* d_out, int out_size, void* d_ws, size_t ws_size,
                              hipStream_t stream) {
    const float* emb  = (const float*)d_in[0];
    const int*   batch= (const int*)d_in[1];
    // d_in[2] = num_molecules (scalar, device) — use out_size instead
    const float* aW1  = (const float*)d_in[3];
    const float* ab1  = (const float*)d_in[4];
    const float* aW2  = (const float*)d_in[5];
    const float* ab2  = (const float*)d_in[6];
    const float* gW1  = (const float*)d_in[7];
    const float* gb1  = (const float*)d_in[8];
    const float* gW2  = (const float*)d_in[9];
    const float* gb2  = (const float*)d_in[10];
    const float* gW3  = (const float*)d_in[11];
    const float* gb3  = (const float*)d_in[12];
    float* outp = (float*)d_out;

    int N = in_sizes[0] / H;
    int M = out_size;

    char* ws = (char*)d_ws;
    float* logits = (float*)ws;                                   // N*4 <= 2 MB
    float* mol    = (float*)(ws + (2u<<20));                      // M*256*4 = 8 MB
    h2*    aW1P   = (h2*)  (ws + (2u<<20) + (8u<<20));            // 64 KB
    float* gW1P   = (float*)(ws + (2u<<20) + (8u<<20) + 65536);   // 256 KB
    float* gW2P   = (float*)(ws + (2u<<20) + (8u<<20) + 65536 + 262144); // 128 KB

    k0_pack<<<64, 256, 0, stream>>>(aW1, gW1, gW2, aW1P, gW1P, gW2P);
    k1_scores<<<(N + TM - 1)/TM, 256, 0, stream>>>(emb, aW1P, ab1, aW2, ab2, logits, N);
    k2_pool<<<M, 256, 0, stream>>>(emb, batch, logits, mol, N);
    k3_mlp<<<(M + 31)/32, 256, 0, stream>>>(mol, gW1P, gb1, gW2P, gb2, gW3, gb3, outp, M);
}

// Round 2
// 320.649 us; speedup vs baseline: 1.5776x; 1.5776x over previous
//
#include <hip/hip_runtime.h>
#include <hip/hip_bf16.h>

#define H   256
#define HH  128
#define TM  64

typedef _Float16 f16x8 __attribute__((ext_vector_type(8)));
typedef float    f32x4 __attribute__((ext_vector_type(4)));

// ---------------------------------------------------------------- K0: pack weights
// aW1F: fp16 fragment-ordered: chunk e8 = ((nt*8+kk)*64+l), 8 halfs:
//   j = nt*16 + (l&15), k = kk*32 + (l>>4)*8 + e   -> aW1[k*128+j]
// gW1P: f32[kq][j][s] = gW1[(kq*4+s)*256 + j]
// gW2P: f32[kq][j][s] = gW2[(kq*4+s)*128 + j]
__global__ __launch_bounds__(256) void k0_pack(
    const float* __restrict__ aW1, const float* __restrict__ gW1,
    const float* __restrict__ gW2,
    _Float16* __restrict__ aW1F, float* __restrict__ gW1P, float* __restrict__ gW2P)
{
    int idx = blockIdx.x * 256 + threadIdx.x;
    int stride = gridDim.x * 256;
    for (int e8 = idx; e8 < 4096; e8 += stride) {
        int l = e8 & 63, kknt = e8 >> 6;
        int kk = kknt & 7, nt = kknt >> 3;
        int j = nt*16 + (l & 15);
        int kbase = kk*32 + (l >> 4)*8;
        f16x8 v;
        #pragma unroll
        for (int e = 0; e < 8; ++e) v[e] = (_Float16)aW1[(kbase + e)*128 + j];
        *reinterpret_cast<f16x8*>(aW1F + e8*8) = v;
    }
    for (int e = idx; e < 64*256*4; e += stride) {
        int s = e & 3, j = (e >> 2) & 255, kq = e >> 10;
        gW1P[e] = gW1[(kq*4+s)*256 + j];
    }
    for (int e = idx; e < 64*128*4; e += stride) {
        int s = e & 3, j = (e >> 2) & 127, kq = e >> 9;
        gW2P[e] = gW2[(kq*4+s)*128 + j];
    }
}

// ---------------------------------------------------------------- K2a: segment starts
__global__ __launch_bounds__(256) void k2a_starts(
    const int* __restrict__ batch, int* __restrict__ starts, int N, int M)
{
    int i = blockIdx.x * 256 + threadIdx.x;
    if (i >= N) return;
    int b = batch[i];
    if (i == 0) {
        for (int m = 0; m <= b; ++m) starts[m] = 0;
    } else {
        int p = batch[i-1];
        for (int m = p + 1; m <= b; ++m) starts[m] = i;
    }
    if (i == N - 1) {
        for (int m = b + 1; m <= M; ++m) starts[m] = N;
    }
}

// ---------------------------------------------------------------- K1: score MLP via MFMA -> logits[N]
// block: 256 thr = 4 waves. Wave w owns hidden cols [32w, 32w+32).
// Per grid-stride tile: 64 rows staged fp16 in LDS (XOR-swizzled), 64 MFMA/wave.
__global__ __launch_bounds__(256) void k1_mfma(
    const float* __restrict__ emb, const _Float16* __restrict__ aW1F,
    const float* __restrict__ ab1, const float* __restrict__ aW2,
    const float* __restrict__ ab2, float* __restrict__ logits,
    int N, int ntiles)
{
    __shared__ __align__(16) _Float16 lds[TM * H];   // 32 KB
    __shared__ float pr[4][TM];
    const int t = threadIdx.x, w = t >> 6, l = t & 63;

    // B fragments: 2 n-tiles x 8 k-steps, 8 halfs each (64 VGPR)
    f16x8 bf[2][8];
    #pragma unroll
    for (int nt2 = 0; nt2 < 2; ++nt2)
        #pragma unroll
        for (int kk = 0; kk < 8; ++kk)
            bf[nt2][kk] = *reinterpret_cast<const f16x8*>(
                aW1F + (size_t)(((2*w + nt2)*8 + kk)*64 + l)*8);

    float b1v[2], w2v[2];
    #pragma unroll
    for (int nt2 = 0; nt2 < 2; ++nt2) {
        int j = 32*w + nt2*16 + (l & 15);
        b1v[nt2] = ab1[j];
        w2v[nt2] = aW2[j];
    }
    float bo = ab2[0];

    char* ldsb = reinterpret_cast<char*>(lds);
    const f32x4 zero = {0.f, 0.f, 0.f, 0.f};

    for (int tile = blockIdx.x; tile < ntiles; tile += gridDim.x) {
        long row0 = (long)tile * TM;
        __syncthreads();
        // stage 64x256 fp32 -> fp16 LDS, swizzled
        #pragma unroll
        for (int i = 0; i < 8; ++i) {
            int cid = i*256 + t;          // 8-float chunk, 0..2047
            int r = cid >> 5, c8 = cid & 31;
            long row = row0 + r;
            float4 v0 = make_float4(0.f,0.f,0.f,0.f);
            float4 v1 = v0;
            if (row < N) {
                const float4* p = reinterpret_cast<const float4*>(emb + row*H) + c8*2;
                v0 = p[0]; v1 = p[1];
            }
            f16x8 hv;
            hv[0]=(_Float16)v0.x; hv[1]=(_Float16)v0.y; hv[2]=(_Float16)v0.z; hv[3]=(_Float16)v0.w;
            hv[4]=(_Float16)v1.x; hv[5]=(_Float16)v1.y; hv[6]=(_Float16)v1.z; hv[7]=(_Float16)v1.w;
            int wb = (r*512 + c8*16) ^ ((r & 7) << 4);
            *reinterpret_cast<f16x8*>(ldsb + wb) = hv;
        }
        __syncthreads();

        f32x4 acc[4][2];
        #pragma unroll
        for (int rt = 0; rt < 4; ++rt) { acc[rt][0] = zero; acc[rt][1] = zero; }

        #pragma unroll
        for (int kk = 0; kk < 8; ++kk) {
            #pragma unroll
            for (int rt = 0; rt < 4; ++rt) {
                int row = rt*16 + (l & 15);
                int rb = (row*512 + kk*64 + (l >> 4)*16) ^ ((row & 7) << 4);
                f16x8 af = *reinterpret_cast<const f16x8*>(ldsb + rb);
                acc[rt][0] = __builtin_amdgcn_mfma_f32_16x16x32_f16(af, bf[0][kk], acc[rt][0], 0, 0, 0);
                acc[rt][1] = __builtin_amdgcn_mfma_f32_16x16x32_f16(af, bf[1][kk], acc[rt][1], 0, 0, 0);
            }
        }

        // epilogue: bias+relu+aW2 dot, reduce cols
        #pragma unroll
        for (int rt = 0; rt < 4; ++rt) {
            #pragma unroll
            for (int r = 0; r < 4; ++r) {
                float h0 = acc[rt][0][r] + b1v[0]; h0 = h0 > 0.f ? h0 : 0.f;
                float h1 = acc[rt][1][r] + b1v[1]; h1 = h1 > 0.f ? h1 : 0.f;
                float p = h0*w2v[0] + h1*w2v[1];
                p += __shfl_xor(p, 1, 64);
                p += __shfl_xor(p, 2, 64);
                p += __shfl_xor(p, 4, 64);
                p += __shfl_xor(p, 8, 64);
                if ((l & 15) == 0) pr[w][rt*16 + (l >> 4)*4 + r] = p;
            }
        }
        __syncthreads();
        if (t < TM) {
            long row = row0 + t;
            if (row < N) logits[row] = pr[0][t] + pr[1][t] + pr[2][t] + pr[3][t] + bo;
        }
    }
}

// ---------------------------------------------------------------- K2: segment softmax + weighted pool
__global__ __launch_bounds__(256) void k2_pool(
    const float* __restrict__ emb, const int* __restrict__ starts,
    const float* __restrict__ logits, float* __restrict__ mol)
{
    int m = blockIdx.x;
    int t = threadIdx.x;
    int start = starts[m], end = starts[m+1];

    if (start >= end) { mol[(long)m*H + t] = 0.f; return; }

    __shared__ float red[8];
    __shared__ float wl[1024];

    // max
    float mx = -INFINITY;
    for (int i = start + t; i < end; i += 256) mx = fmaxf(mx, logits[i]);
    #pragma unroll
    for (int off = 32; off >= 1; off >>= 1) mx = fmaxf(mx, __shfl_xor(mx, off, 64));
    if ((t & 63) == 0) red[t >> 6] = mx;
    __syncthreads();
    mx = fmaxf(fmaxf(red[0], red[1]), fmaxf(red[2], red[3]));
    __syncthreads();

    // denom
    float s = 0.f;
    for (int i = start + t; i < end; i += 256) s += __expf(logits[i] - mx);
    #pragma unroll
    for (int off = 32; off >= 1; off >>= 1) s += __shfl_xor(s, off, 64);
    if ((t & 63) == 0) red[t >> 6] = s;
    __syncthreads();
    s = red[0] + red[1] + red[2] + red[3];
    float inv = 1.0f / s;

    // weighted sum; thread t owns embedding dim t
    float acc = 0.f;
    for (int c = start; c < end; c += 1024) {
        int cnt = min(1024, end - c);
        __syncthreads();
        for (int ii = t; ii < cnt; ii += 256) wl[ii] = __expf(logits[c + ii] - mx) * inv;
        __syncthreads();
        #pragma unroll 4
        for (int ii = 0; ii < cnt; ++ii) acc += wl[ii] * emb[(long)(c + ii)*H + t];
    }
    mol[(long)m*H + t] = acc;
}

// ---------------------------------------------------------------- K3: molecule MLP -> out[M]
__global__ __launch_bounds__(256) void k3_mlp(
    const float* __restrict__ mol, const float* __restrict__ gW1P,
    const float* __restrict__ gb1, const float* __restrict__ gW2P,
    const float* __restrict__ gb2, const float* __restrict__ gW3,
    const float* __restrict__ gb3, float* __restrict__ out, int M)
{
    __shared__ __align__(16) float mt[32 * 256];
    __shared__ __align__(16) float g1[32 * 256];
    __shared__ float tmp[4][16];
    int t = threadIdx.x;
    int blk = blockIdx.x;

    #pragma unroll
    for (int i = 0; i < 8; ++i) {
        int f = t + i*256;
        long gidx = (long)blk*2048 + f;
        float4 v = make_float4(0.f,0.f,0.f,0.f);
        if (gidx < (long)M*64) v = reinterpret_cast<const float4*>(mol)[gidx];
        reinterpret_cast<float4*>(mt)[f] = v;
    }
    __syncthreads();

    int j = t & 127, mh = t >> 7;

    float a0[16], a1[16];
    #pragma unroll
    for (int m = 0; m < 16; ++m) { a0[m] = 0.f; a1[m] = 0.f; }
    for (int kq = 0; kq < 64; ++kq) {
        float4 w0 = reinterpret_cast<const float4*>(gW1P)[kq*256 + j];
        float4 w1 = reinterpret_cast<const float4*>(gW1P)[kq*256 + j + 128];
        #pragma unroll
        for (int m = 0; m < 16; ++m) {
            float4 e = *reinterpret_cast<const float4*>(&mt[(mh*16 + m)*256 + kq*4]);
            a0[m] += e.x*w0.x + e.y*w0.y + e.z*w0.z + e.w*w0.w;
            a1[m] += e.x*w1.x + e.y*w1.y + e.z*w1.z + e.w*w1.w;
        }
    }
    {
        float b0 = gb1[j], b1 = gb1[j + 128];
        #pragma unroll
        for (int m = 0; m < 16; ++m) {
            float v0 = a0[m] + b0; v0 = v0 > 0.f ? v0 : 0.f;
            float v1 = a1[m] + b1; v1 = v1 > 0.f ? v1 : 0.f;
            g1[(mh*16 + m)*256 + j]       = v0;
            g1[(mh*16 + m)*256 + j + 128] = v1;
        }
    }
    __syncthreads();

    float a2[16];
    #pragma unroll
    for (int m = 0; m < 16; ++m) a2[m] = 0.f;
    for (int kq = 0; kq < 64; ++kq) {
        float4 w = reinterpret_cast<const float4*>(gW2P)[kq*128 + j];
        #pragma unroll
        for (int m = 0; m < 16; ++m) {
            float4 e = *reinterpret_cast<const float4*>(&g1[(mh*16 + m)*256 + kq*4]);
            a2[m] += e.x*w.x + e.y*w.y + e.z*w.z + e.w*w.w;
        }
    }

    float b2 = gb2[j], w3 = gW3[j];
    float p[16];
    #pragma unroll
    for (int m = 0; m < 16; ++m) {
        float v = a2[m] + b2; v = v > 0.f ? v : 0.f;
        p[m] = v * w3;
    }
    #pragma unroll
    for (int off = 32; off >= 1; off >>= 1) {
        #pragma unroll
        for (int m = 0; m < 16; ++m) p[m] += __shfl_xor(p[m], off, 64);
    }
    int wid = t >> 6;
    if ((t & 63) == 0) {
        #pragma unroll
        for (int m = 0; m < 16; ++m) tmp[wid][m] = p[m];
    }
    __syncthreads();
    if (t < 32) {
        int om = blk*32 + t;
        if (om < M) out[om] = tmp[(t >> 4)*2][t & 15] + tmp[(t >> 4)*2 + 1][t & 15] + gb3[0];
    }
}

// ---------------------------------------------------------------- launch
extern "C" void kernel_launch(void* const* d_in, const int* in_sizes, int n_in,
                              void* d_out, int out_size, void* d_ws, size_t ws_size,
                              hipStream_t stream) {
    const float* emb  = (const float*)d_in[0];
    const int*   batch= (const int*)d_in[1];
    const float* aW1  = (const float*)d_in[3];
    const float* ab1  = (const float*)d_in[4];
    const float* aW2  = (const float*)d_in[5];
    const float* ab2  = (const float*)d_in[6];
    const float* gW1  = (const float*)d_in[7];
    const float* gb1  = (const float*)d_in[8];
    const float* gW2  = (const float*)d_in[9];
    const float* gb2  = (const float*)d_in[10];
    const float* gW3  = (const float*)d_in[11];
    const float* gb3  = (const float*)d_in[12];
    float* outp = (float*)d_out;

    int N = in_sizes[0] / H;
    int M = out_size;

    char* ws = (char*)d_ws;
    size_t off = 0;
    float*     logits = (float*)(ws + off);  off += (2u<<20);
    float*     mol    = (float*)(ws + off);  off += (8u<<20);
    _Float16*  aW1F   = (_Float16*)(ws + off); off += 65536;
    float*     gW1P   = (float*)(ws + off);  off += 262144;
    float*     gW2P   = (float*)(ws + off);  off += 131072;
    int*       starts = (int*)(ws + off);    off += (size_t)(M+1)*4;

    int ntiles = (N + TM - 1) / TM;
    int grid1 = ntiles < 2048 ? ntiles : 2048;

    k0_pack<<<64, 256, 0, stream>>>(aW1, gW1, gW2, aW1F, gW1P, gW2P);
    k2a_starts<<<(N + 255)/256, 256, 0, stream>>>(batch, starts, N, M);
    k1_mfma<<<grid1, 256, 0, stream>>>(emb, aW1F, ab1, aW2, ab2, logits, N, ntiles);
    k2_pool<<<M, 256, 0, stream>>>(emb, starts, logits, mol);
    k3_mlp<<<(M + 31)/32, 256, 0, stream>>>(mol, gW1P, gb1, gW2P, gb2, gW3, gb3, outp, M);
}